// Round 16
// baseline (88.393 us; speedup 1.0000x reference)
//
#include <hip/hip_runtime.h>
#include <hip/hip_bf16.h>

#define NC 2048       // combined rows: [0,1024) = left, [1024,2048) = right
#define NPAIR 1048576

typedef __attribute__((ext_vector_type(8))) short bf16x8;
typedef __attribute__((ext_vector_type(4))) float f32x4;
typedef __attribute__((ext_vector_type(2))) float f32x2;
typedef __attribute__((ext_vector_type(4))) unsigned int u32x4;

__device__ inline short f2bf(float f) {
    __hip_bfloat16 h = __float2bfloat16(f);
    return __builtin_bit_cast(short, h);
}
__device__ inline unsigned cvt_pk(float a, float b) {   // lo=bf16(a), hi=bf16(b), RNE
    unsigned r;
    asm("v_cvt_pk_bf16_f32 %0, %1, %2" : "=v"(r) : "v"(a), "v"(b));
    return r;
}
__device__ inline float bfu_lo(unsigned u) { return __builtin_bit_cast(float, u << 16); }
__device__ inline float bfu_hi(unsigned u) { return __builtin_bit_cast(float, u & 0xFFFF0000u); }

// ---------------- K0: setup = xej mean (wave-parallel) + weight prep ----------------
__global__ void k_setup(const float* __restrict__ el, const float* __restrict__ er,
                        const float* __restrict__ Wc1, const float* __restrict__ Wn1, const float* __restrict__ We1,
                        const float* __restrict__ Wc2, const float* __restrict__ Wn2, const float* __restrict__ We2,
                        const float* __restrict__ Wc3, const float* __restrict__ Wn3, const float* __restrict__ We3,
                        const float* __restrict__ A1,  const float* __restrict__ A2,  const float* __restrict__ A3,
                        float* __restrict__ xej,
                        float* __restrict__ WT1, float* __restrict__ WT2, float* __restrict__ WT3,
                        float* __restrict__ A1t, short* __restrict__ Bpp) {
    int t = threadIdx.x;
    if (blockIdx.x < 512) {                // xej: one wave per row, 4 rows/block
        int w = t >> 6, l = t & 63;
        int c = blockIdx.x * 4 + w;
        const float* e = ((c < 1024) ? el : er) + (c & 1023) * 1024;
        f32x4 s = {0.f, 0.f, 0.f, 0.f};
#pragma unroll
        for (int q = 0; q < 4; ++q) {
            f32x4 v = *(const f32x4*)(e + q * 256 + l * 4);   // coalesced 1KB/wave
#pragma unroll
            for (int ee = 0; ee < 4; ++ee) s[ee] += v[ee];
        }
#pragma unroll
        for (int m = 8; m < 64; m <<= 1) {                    // reduce over k-groups
#pragma unroll
            for (int ee = 0; ee < 4; ++ee) s[ee] += __shfl_xor(s[ee], m, 64);
        }
        if (l < 8) {
#pragma unroll
            for (int ee = 0; ee < 4; ++ee) s[ee] *= (1.f / 32.f);
            *(f32x4*)&xej[c * 32 + l * 4] = s;
        }
        return;
    }
    int i = (blockIdx.x - 512) * 256 + t;
    if (i < 20480) {                       // WT1: (160 x 128), K-major
        int d = i >> 7, o = i & 127;
        WT1[i] = (d < 64) ? Wc1[o * 64 + d] : (d < 128) ? Wn1[o * 64 + (d - 64)] : We1[o * 32 + (d - 128)];
    } else if (i < 57344) {                // WT2: (288 x 128)
        int j = i - 20480; int d = j >> 7, o = j & 127;
        WT2[j] = (d < 128) ? Wc2[o * 128 + d] : (d < 256) ? Wn2[o * 128 + (d - 128)] : We2[o * 32 + (d - 256)];
    } else if (i < 75776) {                // WT3: (288 x 64)
        int j = i - 57344; int d = j >> 6, o = j & 63;
        WT3[j] = (d < 128) ? Wc3[o * 128 + d] : (d < 256) ? Wn3[o * 128 + (d - 128)] : We3[o * 32 + (d - 256)];
    } else if (i < 83968) {                // A1t: (64 x 128), 0.5 folded in
        int j = i - 75776; int d = j >> 7, o = j & 127;
        A1t[j] = 0.5f * A1[o * 64 + d];
    } else if (i < 92160) {                // A2 frags: permuted h2 rows
        int j = i - 83968;
        int ktnt = j >> 9, l = (j >> 3) & 63, e = j & 7;
        int kt = ktnt >> 2, nt = ktnt & 3;
        int m = l & 15;
        int o = (nt >> 1) * 32 + (m >> 2) * 8 + (nt & 1) * 4 + (m & 3);
        int k = kt * 32 + (l >> 4) * 8 + e;
        Bpp[j] = f2bf(A2[o * 128 + k]);
    } else if (i < 94208) {                // A3 frags: hi/lo split
        int j = i - 92160;
        int cp = j >> 9, l = (j >> 3) & 63, e = j & 7;
        int c = cp >> 1, p = cp & 1;
        int m = l & 15;
        int h2 = c * 32 + (l >> 4) * 8 + e;
        float v = (m < 2) ? A3[m * 64 + h2] : 0.f;
        short hi = f2bf(v);
        float vh = __bfloat162float(__builtin_bit_cast(__hip_bfloat16, hi));
        Bpp[8192 + j] = p ? f2bf(v - vh) : hi;
    }
}

// ---------------- fused gather+GEMM layer: 4 cols/block, weights chunk-staged (r10 proven) ----------------
template<int NIN, int K, int NOUT, bool FUSE_U>
__global__ __launch_bounds__(256) void k_layer(
        const float* __restrict__ xl, const float* __restrict__ xr,
        const int* __restrict__ ijl, const int* __restrict__ ijr,
        const float* __restrict__ xej, const float* __restrict__ WT,
        const float* __restrict__ A1t, float* __restrict__ Y) {
    const int KP = K + 4;
    __shared__ float ct[4 * KP];
    __shared__ float wts[64 * 128];          // 32KB chunk buffer (also holds A1t)
    __shared__ float x3s[4 * 64];
    int t = threadIdx.x;
    int w = t >> 6, l = t & 63;
    int c0 = blockIdx.x * 4;
    // x part
    if (NIN == 128) {
#pragma unroll
        for (int p = 0; p < 2; ++p) {
            int col = p * 2 + (t >> 7), d = t & 127;
            int c = c0 + col, n = c & 1023;
            const float* xp = (c < 1024) ? xl : xr;
            ct[col * KP + d] = xp[n * NIN + d];
        }
    } else {
        int col = t >> 6, d = t & 63;
        int c = c0 + col, n = c & 1023;
        const float* xp = (c < 1024) ? xl : xr;
        ct[col * KP + d] = xp[n * NIN + d];
    }
    // neighbor-mean + edge-mean (one wave per column; n wave-uniform)
    {
        int col = w, c = c0 + col, n = c & 1023;
        const float* xp = (c < 1024) ? xl : xr;
        const int* ijp = (c < 1024) ? ijl : ijr;
        int nb = __builtin_amdgcn_readfirstlane(n);
        if (NIN == 128) {
            int d2 = l * 2;
            float s0 = 0.f, s1 = 0.f;
#pragma unroll
            for (int k = 0; k < 32; ++k) {
                int nh = ijp[nb * 32 + k];                 // s_load (uniform)
                f32x2 v = *(const f32x2*)&xp[nh * NIN + d2];
                s0 += v[0]; s1 += v[1];
            }
            ct[col * KP + NIN + d2]     = s0 * (1.f / 32.f);
            ct[col * KP + NIN + d2 + 1] = s1 * (1.f / 32.f);
        } else {
            float s = 0.f;
#pragma unroll
            for (int k = 0; k < 32; ++k) {
                int nh = ijp[nb * 32 + k];
                s += xp[nh * NIN + l];
            }
            ct[col * KP + NIN + l] = s * (1.f / 32.f);
        }
        if (l < 32) ct[col * KP + 2 * NIN + l] = xej[c * 32 + l];
    }
    // GEMM: wave w owns column w; weights staged in 64-row LDS chunks
    int col = w, c = c0 + col;
    float a0 = 0.f, a1 = 0.f;
    for (int d0 = 0; d0 < K; d0 += 64) {
        int cl = (K - d0 < 64) ? (K - d0) : 64;
        __syncthreads();                                   // gather done / prev chunk done
        for (int idx = t * 4; idx < cl * NOUT; idx += 1024)
            *(f32x4*)&wts[idx] = *(const f32x4*)&WT[d0 * NOUT + idx];
        __syncthreads();
#pragma unroll 4
        for (int dd = 0; dd < cl; ++dd) {
            float xd = ct[col * KP + d0 + dd];             // uniform LDS broadcast
            if (NOUT == 128) {
                a0 = fmaf(wts[dd * 128 + l],      xd, a0);
                a1 = fmaf(wts[dd * 128 + 64 + l], xd, a1);
            } else {
                a0 = fmaf(wts[dd * 64 + l], xd, a0);
            }
        }
    }
    if (NOUT == 128) {
        Y[c * 128 + l]      = fmaxf(a0, 0.f);
        Y[c * 128 + 64 + l] = fmaxf(a1, 0.f);
    } else if (!FUSE_U) {
        Y[c * 64 + l] = fmaxf(a0, 0.f);
    } else {
        // U = 0.5*A1 @ x3 (0.5 folded into A1t), A1t staged into wts buffer
        x3s[col * 64 + l] = fmaxf(a0, 0.f);
        __syncthreads();
        for (int idx = t * 4; idx < 64 * 128; idx += 1024)
            *(f32x4*)&wts[idx] = *(const f32x4*)&A1t[idx];
        __syncthreads();
        float u0 = 0.f, u1 = 0.f;
#pragma unroll 4
        for (int d = 0; d < 64; ++d) {
            float xd = x3s[col * 64 + d];
            u0 = fmaf(wts[d * 128 + l],      xd, u0);
            u1 = fmaf(wts[d * 128 + 64 + l], xd, u1);
        }
        Y[c * 128 + l]      = u0;
        Y[c * 128 + 64 + l] = u1;
    }
}

// ---------------- dense over 1M pairs: jg-OUTER, a2/urb reads amortized over 4 i-rows ----------------
// LDS reads per wave: 4 jg x (16 a2 + 4 urb) = 80 b128 (was 320). Ul refetched per
// (jg,ii) from L2 (16-lane broadcast), hidden under MFMA. Arithmetic bit-identical to r15.
__global__ __launch_bounds__(256) void k_dense(const float* __restrict__ U,
                                               const short* __restrict__ Bpp,
                                               float* __restrict__ out) {
    __shared__ short urb[64 * 128];          // 16KB bf16 Ur tile, byte ^= (row&7)<<4
    __shared__ short bpls[10240];            // 20KB fragment pool (A2 + A3)
    int t = threadIdx.x;
    int lane = t & 63;
    int w = t >> 6;
    int j0 = blockIdx.x * 64;
    int col = lane & 15, g = lane >> 4;

    // stage Ur tile as bf16, swizzled (r10-proven, 4 iters)
#pragma unroll
    for (int it = 0; it < 4; ++it) {
        int idx = t + it * 256;              // 0..1023
        int r = idx >> 4, k8 = idx & 15;
        const float* src = &U[(1024 + j0 + r) * 128 + k8 * 8];
        f32x4 a = *(const f32x4*)src, b = *(const f32x4*)(src + 4);
        u32x4 pw;
        pw[0] = cvt_pk(a[0], a[1]);
        pw[1] = cvt_pk(a[2], a[3]);
        pw[2] = cvt_pk(b[0], b[1]);
        pw[3] = cvt_pk(b[2], b[3]);
        int byte = r * 256 + ((k8 * 16) ^ ((r & 7) << 4));
        *(u32x4*)((char*)urb + byte) = pw;
    }
    // stage fragment pool: 1280 x 16B over 256 threads (5 iters)
    for (int idx = t; idx < 1280; idx += 256)
        *(u32x4*)&bpls[idx * 8] = *(const u32x4*)&Bpp[idx * 8];

    __syncthreads();

    // A3 frags persistent (only 16 VGPR)
    bf16x8 a3f[2][2];
#pragma unroll
    for (int c = 0; c < 2; ++c)
#pragma unroll
        for (int p = 0; p < 2; ++p)
            a3f[c][p] = *(const bf16x8*)&bpls[8192 + ((c * 2 + p) * 64 + lane) * 8];

    const f32x4 z4 = {0.f, 0.f, 0.f, 0.f};
    const int xr = (col & 7) << 4;           // row&7 == col&7 (rows step by 16)

    for (int jg = 0; jg < 4; ++jg) {
        unsigned bofs = 0;
        asm volatile("" : "+v"(bofs));       // opaque 0: block LICM of a2 reads out of jg loop
        int rbase = (jg * 16 + col) * 256;
        // packed Ur words for this jg: 4 b128, reused across 4 i-rows
        u32x4 uw[4];
#pragma unroll
        for (int kt = 0; kt < 4; ++kt)
            uw[kt] = *(const u32x4*)((const char*)urb + rbase + (((kt * 64) | (g * 16)) ^ xr));
        // A2 fragments for this jg: 16 b128, reused across 4 i-rows
        bf16x8 a2f[16];
#pragma unroll
        for (int f = 0; f < 16; ++f)
            a2f[f] = *(const bf16x8*)&bpls[bofs + (f * 64 + lane) * 8];

        for (int ii = 0; ii < 4; ++ii) {
            int i = blockIdx.y * 16 + w * 4 + ii;
            const float* ulp = U + i * 128 + g * 8;   // L2-resident, 16-lane broadcast
            bf16x8 h1f[4];
#pragma unroll
            for (int kt = 0; kt < 4; ++kt) {
                f32x4 u0 = *(const f32x4*)(ulp + kt * 32);
                f32x4 u1 = *(const f32x4*)(ulp + kt * 32 + 4);
                f32x4 ur0 = {bfu_lo(uw[kt][0]), bfu_hi(uw[kt][0]), bfu_lo(uw[kt][1]), bfu_hi(uw[kt][1])};
                f32x4 ur1 = {bfu_lo(uw[kt][2]), bfu_hi(uw[kt][2]), bfu_lo(uw[kt][3]), bfu_hi(uw[kt][3])};
                f32x4 s0 = __builtin_elementwise_max(u0 + ur0, z4);   // v_pk_add/max
                f32x4 s1 = __builtin_elementwise_max(u1 + ur1, z4);
                u32x4 pw;
                pw[0] = cvt_pk(s0[0], s0[1]);
                pw[1] = cvt_pk(s0[2], s0[3]);
                pw[2] = cvt_pk(s1[0], s1[1]);
                pw[3] = cvt_pk(s1[2], s1[3]);
                h1f[kt] = __builtin_bit_cast(bf16x8, pw);
            }
            f32x4 acc1[4] = {{0,0,0,0},{0,0,0,0},{0,0,0,0},{0,0,0,0}};
#pragma unroll
            for (int nt = 0; nt < 4; ++nt)
#pragma unroll
                for (int kt = 0; kt < 4; ++kt)
                    acc1[nt] = __builtin_amdgcn_mfma_f32_16x16x32_bf16(a2f[kt * 4 + nt], h1f[kt], acc1[nt], 0, 0, 0);

            f32x4 accO = {0, 0, 0, 0};
#pragma unroll
            for (int c = 0; c < 2; ++c) {
                f32x4 r0 = __builtin_elementwise_max(acc1[2 * c],     z4);
                f32x4 r1 = __builtin_elementwise_max(acc1[2 * c + 1], z4);
                u32x4 pw;
                pw[0] = cvt_pk(r0[0], r0[1]);
                pw[1] = cvt_pk(r0[2], r0[3]);
                pw[2] = cvt_pk(r1[0], r1[1]);
                pw[3] = cvt_pk(r1[2], r1[3]);
                bf16x8 hb = __builtin_bit_cast(bf16x8, pw);
                accO = __builtin_amdgcn_mfma_f32_16x16x32_bf16(a3f[c][0], hb, accO, 0, 0, 0);
                accO = __builtin_amdgcn_mfma_f32_16x16x32_bf16(a3f[c][1], hb, accO, 0, 0, 0);
            }
            if (lane < 16) {
                int p = i * 1024 + j0 + jg * 16 + col;
                out[p]         = fmaxf(accO[0], 0.f);
                out[NPAIR + p] = fmaxf(accO[1], 0.f);
            }
        }
    }
}

extern "C" void kernel_launch(void* const* d_in, const int* in_sizes, int n_in,
                              void* d_out, int out_size, void* d_ws, size_t ws_size,
                              hipStream_t stream) {
    const float* xnr = (const float*)d_in[0];
    const float* xer = (const float*)d_in[1];
    const int*   ijr = (const int*)  d_in[2];
    const float* xnl = (const float*)d_in[3];
    const float* xel = (const float*)d_in[4];
    const int*   ijl = (const int*)  d_in[5];
    const float* Wc1 = (const float*)d_in[6];
    const float* Wn1 = (const float*)d_in[7];
    const float* We1 = (const float*)d_in[8];
    const float* Wc2 = (const float*)d_in[9];
    const float* Wn2 = (const float*)d_in[10];
    const float* We2 = (const float*)d_in[11];
    const float* Wc3 = (const float*)d_in[12];
    const float* Wn3 = (const float*)d_in[13];
    const float* We3 = (const float*)d_in[14];
    const float* A1  = (const float*)d_in[15];
    const float* A2  = (const float*)d_in[16];
    const float* A3  = (const float*)d_in[17];
    float* out = (float*)d_out;

    float* ws  = (float*)d_ws;
    float* xej = ws;                   // 65536
    float* WT1 = xej + 65536;          // 20480
    float* WT2 = WT1 + 20480;          // 36864
    float* WT3 = WT2 + 36864;          // 18432
    float* A1t = WT3 + 18432;          // 8192
    short* Bpp = (short*)(A1t + 8192); // 10240 shorts = 5120 floats
    float* XA  = A1t + 8192 + 5120;    // 2048*128 = 262144
    float* XB  = XA + 262144;          // 2048*128 = 262144
    float* U   = XB + 262144;          // 2048*128 = 262144

    k_setup<<<880, 256, 0, stream>>>(xel, xer, Wc1, Wn1, We1, Wc2, Wn2, We2, Wc3, Wn3, We3,
                                     A1, A2, A3, xej, WT1, WT2, WT3, A1t, Bpp);
    k_layer<64, 160, 128, false><<<512, 256, 0, stream>>>(xnl, xnr, ijl, ijr, xej, WT1, nullptr, XA);
    k_layer<128, 288, 128, false><<<512, 256, 0, stream>>>(XA, XA + 1024 * 128, ijl, ijr, xej, WT2, nullptr, XB);
    k_layer<128, 288, 64, true><<<512, 256, 0, stream>>>(XB, XB + 1024 * 128, ijl, ijr, xej, WT3, A1t, U);
    k_dense<<<dim3(16, 64), 256, 0, stream>>>(U, Bpp, out);
}

// Round 17
// 78.593 us; speedup vs baseline: 1.1247x; 1.1247x over previous
//
#include <hip/hip_runtime.h>
#include <hip/hip_bf16.h>

#define NC 2048       // combined rows: [0,1024) = left, [1024,2048) = right
#define NPAIR 1048576

typedef __attribute__((ext_vector_type(8))) short bf16x8;
typedef __attribute__((ext_vector_type(4))) float f32x4;
typedef __attribute__((ext_vector_type(2))) float f32x2;
typedef __attribute__((ext_vector_type(4))) unsigned int u32x4;

__device__ inline short f2bf(float f) {
    __hip_bfloat16 h = __float2bfloat16(f);
    return __builtin_bit_cast(short, h);
}
__device__ inline unsigned cvt_pk(float a, float b) {   // lo=bf16(a), hi=bf16(b), RNE
    unsigned r;
    asm("v_cvt_pk_bf16_f32 %0, %1, %2" : "=v"(r) : "v"(a), "v"(b));
    return r;
}
__device__ inline float bfu_lo(unsigned u) { return __builtin_bit_cast(float, u << 16); }
__device__ inline float bfu_hi(unsigned u) { return __builtin_bit_cast(float, u & 0xFFFF0000u); }

// ---------------- fused gather+GEMM layer: 4 cols/block, on-the-fly W transpose ----------------
// L1MODE: computes xej in-block (stores for L2/L3); extra blocks (bid>=512) prep Bpp frags.
template<int NIN, int K, int NOUT, bool FUSE_U, bool L1MODE>
__global__ __launch_bounds__(256) void k_layer(
        const float* __restrict__ xl, const float* __restrict__ xr,
        const int* __restrict__ ijl, const int* __restrict__ ijr,
        const float* __restrict__ el, const float* __restrict__ er,
        float* __restrict__ xejg,
        const float* __restrict__ Wc, const float* __restrict__ Wn, const float* __restrict__ We,
        const float* __restrict__ A1,
        const float* __restrict__ A2, const float* __restrict__ A3, short* __restrict__ Bpp,
        float* __restrict__ Y) {
    const int KP = K + 4;
    __shared__ float ct[4 * KP];
    __shared__ float wts[64 * 129];          // padded: transposed writes conflict-free
    __shared__ float x3s[4 * 64];
    int t = threadIdx.x;
    int w = t >> 6, l = t & 63;

    if (L1MODE && blockIdx.x >= 512) {       // Bpp fragment prep (dense consumes after L3)
        int base = (blockIdx.x - 512) * 1280;
#pragma unroll
        for (int k = 0; k < 5; ++k) {
            int j = base + k * 256 + t;      // j in [0, 10240)
            if (j < 8192) {                  // A2 frags: permuted h2 rows
                int ktnt = j >> 9, l2 = (j >> 3) & 63, e2 = j & 7;
                int kt = ktnt >> 2, nt = ktnt & 3;
                int m = l2 & 15;
                int o = (nt >> 1) * 32 + (m >> 2) * 8 + (nt & 1) * 4 + (m & 3);
                int kk = kt * 32 + (l2 >> 4) * 8 + e2;
                Bpp[j] = f2bf(A2[o * 128 + kk]);
            } else {                         // A3 frags: hi/lo split
                int jj = j - 8192;
                int cp = jj >> 9, l2 = (jj >> 3) & 63, e2 = jj & 7;
                int cc = cp >> 1, p = cp & 1;
                int m = l2 & 15;
                int h2 = cc * 32 + (l2 >> 4) * 8 + e2;
                float v = (m < 2) ? A3[m * 64 + h2] : 0.f;
                short hi = f2bf(v);
                float vh = __bfloat162float(__builtin_bit_cast(__hip_bfloat16, hi));
                Bpp[j] = p ? f2bf(v - vh) : hi;
            }
        }
        return;
    }

    int c0 = blockIdx.x * 4;
    // x part
    if (NIN == 128) {
#pragma unroll
        for (int p = 0; p < 2; ++p) {
            int col = p * 2 + (t >> 7), d = t & 127;
            int c = c0 + col, n = c & 1023;
            const float* xp = (c < 1024) ? xl : xr;
            ct[col * KP + d] = xp[n * NIN + d];
        }
    } else {
        int col = t >> 6, d = t & 63;
        int c = c0 + col, n = c & 1023;
        const float* xp = (c < 1024) ? xl : xr;
        ct[col * KP + d] = xp[n * NIN + d];
    }
    // neighbor-mean (one wave per column; n wave-uniform)
    {
        int col = w, c = c0 + col, n = c & 1023;
        const float* xp = (c < 1024) ? xl : xr;
        const int* ijp = (c < 1024) ? ijl : ijr;
        int nb = __builtin_amdgcn_readfirstlane(n);
        if (NIN == 128) {
            int d2 = l * 2;
            float s0 = 0.f, s1 = 0.f;
#pragma unroll
            for (int k = 0; k < 32; ++k) {
                int nh = ijp[nb * 32 + k];                 // s_load (uniform)
                f32x2 v = *(const f32x2*)&xp[nh * NIN + d2];
                s0 += v[0]; s1 += v[1];
            }
            ct[col * KP + NIN + d2]     = s0 * (1.f / 32.f);
            ct[col * KP + NIN + d2 + 1] = s1 * (1.f / 32.f);
        } else {
            float s = 0.f;
#pragma unroll
            for (int k = 0; k < 32; ++k) {
                int nh = ijp[nb * 32 + k];
                s += xp[nh * NIN + l];
            }
            ct[col * KP + NIN + l] = s * (1.f / 32.f);
        }
        // edge-mean part
        if (L1MODE) {
            // compute xej for this col in-block (same alg as old k_setup -> bit-identical)
            const float* e = ((c < 1024) ? el : er) + (c & 1023) * 1024;
            f32x4 s4 = {0.f, 0.f, 0.f, 0.f};
#pragma unroll
            for (int q = 0; q < 4; ++q) {
                f32x4 v = *(const f32x4*)(e + q * 256 + l * 4);
#pragma unroll
                for (int ee = 0; ee < 4; ++ee) s4[ee] += v[ee];
            }
#pragma unroll
            for (int m = 8; m < 64; m <<= 1) {
#pragma unroll
                for (int ee = 0; ee < 4; ++ee) s4[ee] += __shfl_xor(s4[ee], m, 64);
            }
            if (l < 8) {
#pragma unroll
                for (int ee = 0; ee < 4; ++ee) s4[ee] *= (1.f / 32.f);
                *(f32x4*)&ct[col * KP + 2 * NIN + l * 4] = s4;
                *(f32x4*)&xejg[c * 32 + l * 4] = s4;       // persist for L2/L3
            }
        } else {
            if (l < 32) ct[col * KP + 2 * NIN + l] = xejg[c * 32 + l];
        }
    }
    // GEMM: wave w owns column w; weights transposed on the fly into padded LDS chunks
    int col = w, c = c0 + col;
    float a0 = 0.f, a1 = 0.f;
    for (int d0 = 0; d0 < K; d0 += 64) {
        int cl = (K - d0 < 64) ? (K - d0) : 64;
        const float* Wsrc; int Ksrc, ds0;
        if (d0 < NIN)          { Wsrc = Wc; Ksrc = NIN; ds0 = d0; }
        else if (d0 < 2 * NIN) { Wsrc = Wn; Ksrc = NIN; ds0 = d0 - NIN; }
        else                   { Wsrc = We; Ksrc = 32;  ds0 = 0; }
        __syncthreads();                                   // gather done / prev chunk done
        int q4 = cl >> 2;
        for (int idx = t; idx < NOUT * q4; idx += 256) {
            int o = idx / q4, dq = idx % q4;
            f32x4 v = *(const f32x4*)&Wsrc[o * Ksrc + ds0 + dq * 4];
#pragma unroll
            for (int j = 0; j < 4; ++j)
                wts[(dq * 4 + j) * 129 + o] = v[j];        // 2-way banks: free
        }
        __syncthreads();
#pragma unroll 4
        for (int dd = 0; dd < cl; ++dd) {
            float xd = ct[col * KP + d0 + dd];             // uniform LDS broadcast
            a0 = fmaf(wts[dd * 129 + l], xd, a0);
            if (NOUT == 128) a1 = fmaf(wts[dd * 129 + 64 + l], xd, a1);
        }
    }
    if (NOUT == 128) {
        Y[c * 128 + l]      = fmaxf(a0, 0.f);
        Y[c * 128 + 64 + l] = fmaxf(a1, 0.f);
    } else if (!FUSE_U) {
        Y[c * 64 + l] = fmaxf(a0, 0.f);
    } else {
        // U = 0.5*A1 @ x3 ; A1 transposed on the fly (0.5 folded)
        x3s[col * 64 + l] = fmaxf(a0, 0.f);
        __syncthreads();
        for (int idx = t; idx < 128 * 16; idx += 256) {
            int o = idx / 16, dq = idx % 16;
            f32x4 v = *(const f32x4*)&A1[o * 64 + dq * 4];
#pragma unroll
            for (int j = 0; j < 4; ++j)
                wts[(dq * 4 + j) * 129 + o] = 0.5f * v[j];
        }
        __syncthreads();
        float u0 = 0.f, u1 = 0.f;
#pragma unroll 4
        for (int d = 0; d < 64; ++d) {
            float xd = x3s[col * 64 + d];
            u0 = fmaf(wts[d * 129 + l],      xd, u0);
            u1 = fmaf(wts[d * 129 + 64 + l], xd, u1);
        }
        Y[c * 128 + l]      = u0;
        Y[c * 128 + 64 + l] = u1;
    }
}

// ---------------- dense over 1M pairs: r14 proven version (42.4us, VGPR 60) ----------------
__global__ __launch_bounds__(256) void k_dense(const float* __restrict__ U,
                                               const short* __restrict__ Bpp,
                                               float* __restrict__ out) {
    __shared__ short urb[64 * 128];          // 16KB bf16 Ur tile, byte ^= (row&7)<<4
    __shared__ short bpls[10240];            // 20KB fragment pool (A2 + A3)
    int t = threadIdx.x;
    int lane = t & 63;
    int w = t >> 6;
    int j0 = blockIdx.x * 64;
    int i  = blockIdx.y * 4 + w;
    int col = lane & 15, g = lane >> 4;

    // stage Ur tile as bf16, swizzled (4 iters = full 64x128 tile)
#pragma unroll
    for (int it = 0; it < 4; ++it) {
        int idx = t + it * 256;              // 0..1023
        int r = idx >> 4, k8 = idx & 15;
        const float* src = &U[(1024 + j0 + r) * 128 + k8 * 8];
        f32x4 a = *(const f32x4*)src, b = *(const f32x4*)(src + 4);
        u32x4 pw;
        pw[0] = cvt_pk(a[0], a[1]);
        pw[1] = cvt_pk(a[2], a[3]);
        pw[2] = cvt_pk(b[0], b[1]);
        pw[3] = cvt_pk(b[2], b[3]);
        int byte = r * 256 + ((k8 * 16) ^ ((r & 7) << 4));
        *(u32x4*)((char*)urb + byte) = pw;
    }
    // stage fragment pool: 1280 x 16B over 256 threads (5 iters)
    for (int idx = t; idx < 1280; idx += 256)
        *(u32x4*)&bpls[idx * 8] = *(const u32x4*)&Bpp[idx * 8];

    // Ul slice (persistent f32)
    f32x4 ulq[4][2];
#pragma unroll
    for (int kt = 0; kt < 4; ++kt) {
        const float* p = U + i * 128 + kt * 32 + g * 8;
        ulq[kt][0] = *(const f32x4*)p;
        ulq[kt][1] = *(const f32x4*)(p + 4);
    }

    __syncthreads();

    // A3 frags persistent (only 16 VGPR)
    bf16x8 a3f[2][2];
#pragma unroll
    for (int c = 0; c < 2; ++c)
#pragma unroll
        for (int p = 0; p < 2; ++p)
            a3f[c][p] = *(const bf16x8*)&bpls[8192 + ((c * 2 + p) * 64 + lane) * 8];

    const f32x4 z4 = {0.f, 0.f, 0.f, 0.f};
    const int xr = (col & 7) << 4;           // row&7 == col&7 (rows step by 16)
    for (int jg = 0; jg < 4; ++jg) {
        unsigned bofs = 0;
        asm volatile("" : "+v"(bofs));       // opaque 0: block cross-jg CSE of frag reads
        int rbase = (jg * 16 + col) * 256;
        bf16x8 h1f[4];
#pragma unroll
        for (int kt = 0; kt < 4; ++kt) {
            u32x4 uw = *(const u32x4*)((const char*)urb + rbase + (((kt * 64) | (g * 16)) ^ xr));
            f32x4 ur0 = {bfu_lo(uw[0]), bfu_hi(uw[0]), bfu_lo(uw[1]), bfu_hi(uw[1])};
            f32x4 ur1 = {bfu_lo(uw[2]), bfu_hi(uw[2]), bfu_lo(uw[3]), bfu_hi(uw[3])};
            f32x4 s0 = __builtin_elementwise_max(ulq[kt][0] + ur0, z4);   // v_pk_add/max
            f32x4 s1 = __builtin_elementwise_max(ulq[kt][1] + ur1, z4);
            u32x4 pw;
            pw[0] = cvt_pk(s0[0], s0[1]);
            pw[1] = cvt_pk(s0[2], s0[3]);
            pw[2] = cvt_pk(s1[0], s1[1]);
            pw[3] = cvt_pk(s1[2], s1[3]);
            h1f[kt] = __builtin_bit_cast(bf16x8, pw);
        }
        f32x4 acc1[4] = {{0,0,0,0},{0,0,0,0},{0,0,0,0},{0,0,0,0}};
#pragma unroll
        for (int nt = 0; nt < 4; ++nt)
#pragma unroll
            for (int kt = 0; kt < 4; ++kt) {
                bf16x8 a2 = *(const bf16x8*)&bpls[bofs + ((kt * 4 + nt) * 64 + lane) * 8];
                acc1[nt] = __builtin_amdgcn_mfma_f32_16x16x32_bf16(a2, h1f[kt], acc1[nt], 0, 0, 0);
            }

        f32x4 accO = {0, 0, 0, 0};
#pragma unroll
        for (int c = 0; c < 2; ++c) {
            f32x4 r0 = __builtin_elementwise_max(acc1[2 * c],     z4);
            f32x4 r1 = __builtin_elementwise_max(acc1[2 * c + 1], z4);
            u32x4 pw;
            pw[0] = cvt_pk(r0[0], r0[1]);
            pw[1] = cvt_pk(r0[2], r0[3]);
            pw[2] = cvt_pk(r1[0], r1[1]);
            pw[3] = cvt_pk(r1[2], r1[3]);
            bf16x8 hb = __builtin_bit_cast(bf16x8, pw);
            accO = __builtin_amdgcn_mfma_f32_16x16x32_bf16(a3f[c][0], hb, accO, 0, 0, 0);
            accO = __builtin_amdgcn_mfma_f32_16x16x32_bf16(a3f[c][1], hb, accO, 0, 0, 0);
        }
        if (lane < 16) {
            int p = i * 1024 + j0 + jg * 16 + col;
            out[p]         = fmaxf(accO[0], 0.f);
            out[NPAIR + p] = fmaxf(accO[1], 0.f);
        }
    }
}

extern "C" void kernel_launch(void* const* d_in, const int* in_sizes, int n_in,
                              void* d_out, int out_size, void* d_ws, size_t ws_size,
                              hipStream_t stream) {
    const float* xnr = (const float*)d_in[0];
    const float* xer = (const float*)d_in[1];
    const int*   ijr = (const int*)  d_in[2];
    const float* xnl = (const float*)d_in[3];
    const float* xel = (const float*)d_in[4];
    const int*   ijl = (const int*)  d_in[5];
    const float* Wc1 = (const float*)d_in[6];
    const float* Wn1 = (const float*)d_in[7];
    const float* We1 = (const float*)d_in[8];
    const float* Wc2 = (const float*)d_in[9];
    const float* Wn2 = (const float*)d_in[10];
    const float* We2 = (const float*)d_in[11];
    const float* Wc3 = (const float*)d_in[12];
    const float* Wn3 = (const float*)d_in[13];
    const float* We3 = (const float*)d_in[14];
    const float* A1  = (const float*)d_in[15];
    const float* A2  = (const float*)d_in[16];
    const float* A3  = (const float*)d_in[17];
    float* out = (float*)d_out;

    float* ws  = (float*)d_ws;
    float* xej = ws;                    // 65536
    short* Bpp = (short*)(xej + 65536); // 10240 shorts = 5120 floats
    float* XA  = xej + 65536 + 5120;    // 2048*128 = 262144
    float* XB  = XA + 262144;           // 2048*128 = 262144
    float* U   = XB + 262144;           // 2048*128 = 262144

    // layer 1 (+ xej computation + Bpp prep in 8 extra blocks)
    k_layer<64, 160, 128, false, true><<<520, 256, 0, stream>>>(
        xnl, xnr, ijl, ijr, xel, xer, xej, Wc1, Wn1, We1, nullptr, A2, A3, Bpp, XA);
    // layer 2
    k_layer<128, 288, 128, false, false><<<512, 256, 0, stream>>>(
        XA, XA + 1024 * 128, ijl, ijr, nullptr, nullptr, xej, Wc2, Wn2, We2, nullptr,
        nullptr, nullptr, nullptr, XB);
    // layer 3 + U
    k_layer<128, 288, 64, true, false><<<512, 256, 0, stream>>>(
        XB, XB + 1024 * 128, ijl, ijr, nullptr, nullptr, xej, Wc3, Wn3, We3, A1,
        nullptr, nullptr, nullptr, U);
    // dense over all pairs
    k_dense<<<dim3(16, 256), 256, 0, stream>>>(U, Bpp, out);
}

// Round 18
// 76.230 us; speedup vs baseline: 1.1596x; 1.0310x over previous
//
#include <hip/hip_runtime.h>
#include <hip/hip_bf16.h>

#define NC 2048       // combined rows: [0,1024) = left, [1024,2048) = right
#define NPAIR 1048576

typedef __attribute__((ext_vector_type(8))) short bf16x8;
typedef __attribute__((ext_vector_type(4))) float f32x4;
typedef __attribute__((ext_vector_type(2))) float f32x2;
typedef __attribute__((ext_vector_type(4))) unsigned int u32x4;

__device__ inline short f2bf(float f) {
    __hip_bfloat16 h = __float2bfloat16(f);
    return __builtin_bit_cast(short, h);
}
__device__ inline unsigned cvt_pk(float a, float b) {   // lo=bf16(a), hi=bf16(b), RNE
    unsigned r;
    asm("v_cvt_pk_bf16_f32 %0, %1, %2" : "=v"(r) : "v"(a), "v"(b));
    return r;
}
__device__ inline float bfu_lo(unsigned u) { return __builtin_bit_cast(float, u << 16); }
__device__ inline float bfu_hi(unsigned u) { return __builtin_bit_cast(float, u & 0xFFFF0000u); }

// ---------------- fused gather+GEMM layer: 4 cols/block, on-the-fly W transpose ----------------
// L1MODE: computes xej in-block (stores for L2/L3); extra blocks (bid>=512) prep Bpp frags.
// FUSE_U additionally emits UB = bf16 pre-swizzled copy of U rows (k_dense staging source).
template<int NIN, int K, int NOUT, bool FUSE_U, bool L1MODE>
__global__ __launch_bounds__(256) void k_layer(
        const float* __restrict__ xl, const float* __restrict__ xr,
        const int* __restrict__ ijl, const int* __restrict__ ijr,
        const float* __restrict__ el, const float* __restrict__ er,
        float* __restrict__ xejg,
        const float* __restrict__ Wc, const float* __restrict__ Wn, const float* __restrict__ We,
        const float* __restrict__ A1,
        const float* __restrict__ A2, const float* __restrict__ A3, short* __restrict__ Bpp,
        float* __restrict__ Y, short* __restrict__ UBg) {
    const int KP = K + 4;
    __shared__ float ct[4 * KP];
    __shared__ float wts[64 * 129];          // padded: transposed writes conflict-free
    __shared__ float x3s[4 * 64];
    __shared__ float ubs[4 * 128];
    int t = threadIdx.x;
    int w = t >> 6, l = t & 63;

    if (L1MODE && blockIdx.x >= 512) {       // Bpp fragment prep (dense consumes after L3)
        int base = (blockIdx.x - 512) * 1280;
#pragma unroll
        for (int k = 0; k < 5; ++k) {
            int j = base + k * 256 + t;      // j in [0, 10240)
            if (j < 8192) {                  // A2 frags: permuted h2 rows
                int ktnt = j >> 9, l2 = (j >> 3) & 63, e2 = j & 7;
                int kt = ktnt >> 2, nt = ktnt & 3;
                int m = l2 & 15;
                int o = (nt >> 1) * 32 + (m >> 2) * 8 + (nt & 1) * 4 + (m & 3);
                int kk = kt * 32 + (l2 >> 4) * 8 + e2;
                Bpp[j] = f2bf(A2[o * 128 + kk]);
            } else {                         // A3 frags: hi/lo split
                int jj = j - 8192;
                int cp = jj >> 9, l2 = (jj >> 3) & 63, e2 = jj & 7;
                int cc = cp >> 1, p = cp & 1;
                int m = l2 & 15;
                int h2 = cc * 32 + (l2 >> 4) * 8 + e2;
                float v = (m < 2) ? A3[m * 64 + h2] : 0.f;
                short hi = f2bf(v);
                float vh = __bfloat162float(__builtin_bit_cast(__hip_bfloat16, hi));
                Bpp[j] = p ? f2bf(v - vh) : hi;
            }
        }
        return;
    }

    int c0 = blockIdx.x * 4;
    // x part
    if (NIN == 128) {
#pragma unroll
        for (int p = 0; p < 2; ++p) {
            int col = p * 2 + (t >> 7), d = t & 127;
            int c = c0 + col, n = c & 1023;
            const float* xp = (c < 1024) ? xl : xr;
            ct[col * KP + d] = xp[n * NIN + d];
        }
    } else {
        int col = t >> 6, d = t & 63;
        int c = c0 + col, n = c & 1023;
        const float* xp = (c < 1024) ? xl : xr;
        ct[col * KP + d] = xp[n * NIN + d];
    }
    // neighbor-mean (one wave per column; n wave-uniform)
    {
        int col = w, c = c0 + col, n = c & 1023;
        const float* xp = (c < 1024) ? xl : xr;
        const int* ijp = (c < 1024) ? ijl : ijr;
        int nb = __builtin_amdgcn_readfirstlane(n);
        if (NIN == 128) {
            int d2 = l * 2;
            float s0 = 0.f, s1 = 0.f;
#pragma unroll
            for (int k = 0; k < 32; ++k) {
                int nh = ijp[nb * 32 + k];                 // s_load (uniform)
                f32x2 v = *(const f32x2*)&xp[nh * NIN + d2];
                s0 += v[0]; s1 += v[1];
            }
            ct[col * KP + NIN + d2]     = s0 * (1.f / 32.f);
            ct[col * KP + NIN + d2 + 1] = s1 * (1.f / 32.f);
        } else {
            float s = 0.f;
#pragma unroll
            for (int k = 0; k < 32; ++k) {
                int nh = ijp[nb * 32 + k];
                s += xp[nh * NIN + l];
            }
            ct[col * KP + NIN + l] = s * (1.f / 32.f);
        }
        // edge-mean part
        if (L1MODE) {
            const float* e = ((c < 1024) ? el : er) + (c & 1023) * 1024;
            f32x4 s4 = {0.f, 0.f, 0.f, 0.f};
#pragma unroll
            for (int q = 0; q < 4; ++q) {
                f32x4 v = *(const f32x4*)(e + q * 256 + l * 4);
#pragma unroll
                for (int ee = 0; ee < 4; ++ee) s4[ee] += v[ee];
            }
#pragma unroll
            for (int m = 8; m < 64; m <<= 1) {
#pragma unroll
                for (int ee = 0; ee < 4; ++ee) s4[ee] += __shfl_xor(s4[ee], m, 64);
            }
            if (l < 8) {
#pragma unroll
                for (int ee = 0; ee < 4; ++ee) s4[ee] *= (1.f / 32.f);
                *(f32x4*)&ct[col * KP + 2 * NIN + l * 4] = s4;
                *(f32x4*)&xejg[c * 32 + l * 4] = s4;       // persist for L2/L3
            }
        } else {
            if (l < 32) ct[col * KP + 2 * NIN + l] = xejg[c * 32 + l];
        }
    }
    // GEMM: wave w owns column w; weights transposed on the fly into padded LDS chunks
    int col = w, c = c0 + col;
    float a0 = 0.f, a1 = 0.f;
    for (int d0 = 0; d0 < K; d0 += 64) {
        int cl = (K - d0 < 64) ? (K - d0) : 64;
        const float* Wsrc; int Ksrc, ds0;
        if (d0 < NIN)          { Wsrc = Wc; Ksrc = NIN; ds0 = d0; }
        else if (d0 < 2 * NIN) { Wsrc = Wn; Ksrc = NIN; ds0 = d0 - NIN; }
        else                   { Wsrc = We; Ksrc = 32;  ds0 = 0; }
        __syncthreads();                                   // gather done / prev chunk done
        int q4 = cl >> 2;
        for (int idx = t; idx < NOUT * q4; idx += 256) {
            int o = idx / q4, dq = idx % q4;
            f32x4 v = *(const f32x4*)&Wsrc[o * Ksrc + ds0 + dq * 4];
#pragma unroll
            for (int j = 0; j < 4; ++j)
                wts[(dq * 4 + j) * 129 + o] = v[j];        // 2-way banks: free
        }
        __syncthreads();
#pragma unroll 4
        for (int dd = 0; dd < cl; ++dd) {
            float xd = ct[col * KP + d0 + dd];             // uniform LDS broadcast
            a0 = fmaf(wts[dd * 129 + l], xd, a0);
            if (NOUT == 128) a1 = fmaf(wts[dd * 129 + 64 + l], xd, a1);
        }
    }
    if (NOUT == 128) {
        Y[c * 128 + l]      = fmaxf(a0, 0.f);
        Y[c * 128 + 64 + l] = fmaxf(a1, 0.f);
    } else if (!FUSE_U) {
        Y[c * 64 + l] = fmaxf(a0, 0.f);
    } else {
        // U = 0.5*A1 @ x3 ; A1 transposed on the fly (0.5 folded)
        x3s[col * 64 + l] = fmaxf(a0, 0.f);
        __syncthreads();
        for (int idx = t; idx < 128 * 16; idx += 256) {
            int o = idx / 16, dq = idx % 16;
            f32x4 v = *(const f32x4*)&A1[o * 64 + dq * 4];
#pragma unroll
            for (int j = 0; j < 4; ++j)
                wts[(dq * 4 + j) * 129 + o] = 0.5f * v[j];
        }
        __syncthreads();
        float u0 = 0.f, u1 = 0.f;
#pragma unroll 4
        for (int d = 0; d < 64; ++d) {
            float xd = x3s[col * 64 + d];
            u0 = fmaf(wts[d * 129 + l],      xd, u0);
            u1 = fmaf(wts[d * 129 + 64 + l], xd, u1);
        }
        Y[c * 128 + l]      = u0;
        Y[c * 128 + 64 + l] = u1;
        // UB: bf16 pre-swizzled copy (k_dense stages it with a pure linear copy).
        ubs[col * 128 + l]      = u0;
        ubs[col * 128 + 64 + l] = u1;
        __syncthreads();
        if (l < 16) {
            int j = c0 + w;                                // global row index
            const float* src = &ubs[w * 128 + l * 8];
            u32x4 pw;
            pw[0] = cvt_pk(src[0], src[1]);                // same RNE as old k_dense staging
            pw[1] = cvt_pk(src[2], src[3]);
            pw[2] = cvt_pk(src[4], src[5]);
            pw[3] = cvt_pk(src[6], src[7]);
            *(u32x4*)((char*)UBg + j * 256 + ((l * 16) ^ ((j & 7) << 4))) = pw;
        }
    }
}

// ---------------- dense over 1M pairs: 32KB LDS (5 blocks/CU), copy-only staging ----------------
// urb staged by pure linear b128 copy from pre-swizzled bf16 UB (producer did the cvt+swizzle).
// bpls holds A2 frags only (16KB); a3f read once per wave from global Bpp (L2-cached).
__global__ __launch_bounds__(256) void k_dense(const float* __restrict__ U,
                                               const short* __restrict__ UBg,
                                               const short* __restrict__ Bpp,
                                               float* __restrict__ out) {
    __shared__ short urb[64 * 128];          // 16KB bf16 Ur tile (pre-swizzled)
    __shared__ short bpls[8192];             // 16KB A2 fragment pool
    int t = threadIdx.x;
    int lane = t & 63;
    int w = t >> 6;
    int j0 = blockIdx.x * 64;
    int i  = blockIdx.y * 4 + w;
    int col = lane & 15, g = lane >> 4;

    // stage Ur tile: linear copy of 16KB (swizzle already applied at producer)
    {
        const u32x4* src = (const u32x4*)((const char*)UBg + (1024 + j0) * 256);
        u32x4* dst = (u32x4*)urb;
#pragma unroll
        for (int it = 0; it < 4; ++it)
            dst[t + it * 256] = src[t + it * 256];
    }
    // stage A2 fragment pool: 1024 x 16B
#pragma unroll
    for (int it = 0; it < 4; ++it) {
        int idx = t + it * 256;
        *(u32x4*)&bpls[idx * 8] = *(const u32x4*)&Bpp[idx * 8];
    }

    // Ul slice (persistent f32)
    f32x4 ulq[4][2];
#pragma unroll
    for (int kt = 0; kt < 4; ++kt) {
        const float* p = U + i * 128 + kt * 32 + g * 8;
        ulq[kt][0] = *(const f32x4*)p;
        ulq[kt][1] = *(const f32x4*)(p + 4);
    }
    // A3 frags from global (identical values; one-time, L2-cached)
    bf16x8 a3f[2][2];
#pragma unroll
    for (int c = 0; c < 2; ++c)
#pragma unroll
        for (int p = 0; p < 2; ++p)
            a3f[c][p] = *(const bf16x8*)&Bpp[8192 + ((c * 2 + p) * 64 + lane) * 8];

    __syncthreads();

    const f32x4 z4 = {0.f, 0.f, 0.f, 0.f};
    const int xr = (col & 7) << 4;           // row&7 == col&7 (rows step by 16)
    for (int jg = 0; jg < 4; ++jg) {
        unsigned bofs = 0;
        asm volatile("" : "+v"(bofs));       // opaque 0: block cross-jg CSE of frag reads
        int rbase = (jg * 16 + col) * 256;
        bf16x8 h1f[4];
#pragma unroll
        for (int kt = 0; kt < 4; ++kt) {
            u32x4 uw = *(const u32x4*)((const char*)urb + rbase + (((kt * 64) | (g * 16)) ^ xr));
            f32x4 ur0 = {bfu_lo(uw[0]), bfu_hi(uw[0]), bfu_lo(uw[1]), bfu_hi(uw[1])};
            f32x4 ur1 = {bfu_lo(uw[2]), bfu_hi(uw[2]), bfu_lo(uw[3]), bfu_hi(uw[3])};
            f32x4 s0 = __builtin_elementwise_max(ulq[kt][0] + ur0, z4);   // v_pk_add/max
            f32x4 s1 = __builtin_elementwise_max(ulq[kt][1] + ur1, z4);
            u32x4 pw;
            pw[0] = cvt_pk(s0[0], s0[1]);
            pw[1] = cvt_pk(s0[2], s0[3]);
            pw[2] = cvt_pk(s1[0], s1[1]);
            pw[3] = cvt_pk(s1[2], s1[3]);
            h1f[kt] = __builtin_bit_cast(bf16x8, pw);
        }
        f32x4 acc1[4] = {{0,0,0,0},{0,0,0,0},{0,0,0,0},{0,0,0,0}};
#pragma unroll
        for (int nt = 0; nt < 4; ++nt)
#pragma unroll
            for (int kt = 0; kt < 4; ++kt) {
                bf16x8 a2 = *(const bf16x8*)&bpls[bofs + ((kt * 4 + nt) * 64 + lane) * 8];
                acc1[nt] = __builtin_amdgcn_mfma_f32_16x16x32_bf16(a2, h1f[kt], acc1[nt], 0, 0, 0);
            }

        f32x4 accO = {0, 0, 0, 0};
#pragma unroll
        for (int c = 0; c < 2; ++c) {
            f32x4 r0 = __builtin_elementwise_max(acc1[2 * c],     z4);
            f32x4 r1 = __builtin_elementwise_max(acc1[2 * c + 1], z4);
            u32x4 pw;
            pw[0] = cvt_pk(r0[0], r0[1]);
            pw[1] = cvt_pk(r0[2], r0[3]);
            pw[2] = cvt_pk(r1[0], r1[1]);
            pw[3] = cvt_pk(r1[2], r1[3]);
            bf16x8 hb = __builtin_bit_cast(bf16x8, pw);
            accO = __builtin_amdgcn_mfma_f32_16x16x32_bf16(a3f[c][0], hb, accO, 0, 0, 0);
            accO = __builtin_amdgcn_mfma_f32_16x16x32_bf16(a3f[c][1], hb, accO, 0, 0, 0);
        }
        if (lane < 16) {
            int p = i * 1024 + j0 + jg * 16 + col;
            out[p]         = fmaxf(accO[0], 0.f);
            out[NPAIR + p] = fmaxf(accO[1], 0.f);
        }
    }
}

extern "C" void kernel_launch(void* const* d_in, const int* in_sizes, int n_in,
                              void* d_out, int out_size, void* d_ws, size_t ws_size,
                              hipStream_t stream) {
    const float* xnr = (const float*)d_in[0];
    const float* xer = (const float*)d_in[1];
    const int*   ijr = (const int*)  d_in[2];
    const float* xnl = (const float*)d_in[3];
    const float* xel = (const float*)d_in[4];
    const int*   ijl = (const int*)  d_in[5];
    const float* Wc1 = (const float*)d_in[6];
    const float* Wn1 = (const float*)d_in[7];
    const float* We1 = (const float*)d_in[8];
    const float* Wc2 = (const float*)d_in[9];
    const float* Wn2 = (const float*)d_in[10];
    const float* We2 = (const float*)d_in[11];
    const float* Wc3 = (const float*)d_in[12];
    const float* Wn3 = (const float*)d_in[13];
    const float* We3 = (const float*)d_in[14];
    const float* A1  = (const float*)d_in[15];
    const float* A2  = (const float*)d_in[16];
    const float* A3  = (const float*)d_in[17];
    float* out = (float*)d_out;

    float* ws  = (float*)d_ws;
    float* xej = ws;                    // 65536
    short* Bpp = (short*)(xej + 65536); // 10240 shorts = 5120 floats
    float* XA  = xej + 65536 + 5120;    // 2048*128 = 262144
    float* XB  = XA + 262144;           // 2048*128 = 262144
    float* U   = XB + 262144;           // 2048*128 = 262144
    short* UB  = (short*)(U + 262144);  // 2048*256 bytes = 131072 floats

    // layer 1 (+ xej computation + Bpp prep in 8 extra blocks)
    k_layer<64, 160, 128, false, true><<<520, 256, 0, stream>>>(
        xnl, xnr, ijl, ijr, xel, xer, xej, Wc1, Wn1, We1, nullptr, A2, A3, Bpp, XA, nullptr);
    // layer 2
    k_layer<128, 288, 128, false, false><<<512, 256, 0, stream>>>(
        XA, XA + 1024 * 128, ijl, ijr, nullptr, nullptr, xej, Wc2, Wn2, We2, nullptr,
        nullptr, nullptr, nullptr, XB, nullptr);
    // layer 3 + U (+ UB bf16 pre-swizzled emission)
    k_layer<128, 288, 64, true, false><<<512, 256, 0, stream>>>(
        XB, XB + 1024 * 128, ijl, ijr, nullptr, nullptr, xej, Wc3, Wn3, We3, A1,
        nullptr, nullptr, nullptr, U, UB);
    // dense over all pairs
    k_dense<<<dim3(16, 256), 256, 0, stream>>>(U, UB, Bpp, out);
}